// Round 3
// baseline (4205.038 us; speedup 1.0000x reference)
//
#include <hip/hip_runtime.h>

#define S_LEN 8192
#define HID 2048
#define HKN 8
#define HVN 16
#define DKD 128
#define DVD 128
#define NCHUNK 128
#define CLEN 64
#define NQKV 4096
#define EPSF 1e-6f

typedef unsigned int u32;
typedef unsigned short u16;
typedef __attribute__((ext_vector_type(8))) short s16x8;
typedef __attribute__((ext_vector_type(4))) float f32x4;

__device__ __forceinline__ float bfraw2f(u16 v) { return __uint_as_float(((u32)v) << 16); }
__device__ __forceinline__ u16 f2bf_rne(float f) {
    u32 u = __float_as_uint(f);
    u32 r = u + 0x7fffu + ((u >> 16) & 1u);
    return (u16)(r >> 16);
}
__device__ __forceinline__ void unpack8(uint4 u, float* f) {
    const u32 a[4] = {u.x, u.y, u.z, u.w};
#pragma unroll
    for (int q = 0; q < 4; ++q) {
        f[2*q]   = __uint_as_float(a[q] << 16);
        f[2*q+1] = __uint_as_float(a[q] & 0xffff0000u);
    }
}
__device__ __forceinline__ uint4 pack8(const float* v) {
    uint4 r;
    r.x = (u32)f2bf_rne(v[0]) | ((u32)f2bf_rne(v[1]) << 16);
    r.y = (u32)f2bf_rne(v[2]) | ((u32)f2bf_rne(v[3]) << 16);
    r.z = (u32)f2bf_rne(v[4]) | ((u32)f2bf_rne(v[5]) << 16);
    r.w = (u32)f2bf_rne(v[6]) | ((u32)f2bf_rne(v[7]) << 16);
    return r;
}

// ------------- b,a projections (scalar, broadcast-x) + activations -------------
__global__ __launch_bounds__(256) void ba_kernel(const float* __restrict__ x,
                                                 const float* __restrict__ Wb,
                                                 const float* __restrict__ Wa,
                                                 const float* __restrict__ A_log,
                                                 const float* __restrict__ dt_bias,
                                                 float* __restrict__ beta,
                                                 float* __restrict__ g) {
    const int t = threadIdx.x;
    const int row = blockIdx.x * 8 + (t >> 5);
    const int c = t & 31;
    const int cc = c & 15;
    const float* W = (c < 16) ? Wb : Wa;
    const float* xr = x + (size_t)row * HID;
    float acc = 0.f;
    for (int k = 0; k < HID; ++k) acc = fmaf(xr[k], W[k * 16 + cc], acc);
    if (c < 16) {
        beta[row * 16 + cc] = 1.f / (1.f + expf(-acc));
    } else {
        float v = acc + dt_bias[cc];
        float sp = (v > 20.f) ? v : log1pf(expf(v));
        g[row * 16 + cc] = -expf(A_log[cc]) * sp;
    }
}

// ------------- MFMA GEMM: C[M,N] = A[M,K] * B[K,N], B fp32 row-major [K,N] -------------
// AF32: A operand fp32 (cast at staging) vs bf16. F32OUT: fp32 vs bf16 store.
template <int AF32, int F32OUT>
__global__ __launch_bounds__(256) void gemm_kn(const void* __restrict__ Av,
                                               const float* __restrict__ B,
                                               void* __restrict__ Cv,
                                               int M, int N, int K) {
    __shared__ u16 As[128 * 72];
    __shared__ u16 Bs[128 * 72];
    const int t = threadIdx.x;
    const int n0 = blockIdx.x * 128;
    const int m0 = blockIdx.y * 128;
    const int w = t >> 6, lane = t & 63;
    const int wm = (w >> 1) * 64, wn = (w & 1) * 64;
    const int ml = lane & 15, kq = lane >> 4;
    f32x4 acc[4][4];
#pragma unroll
    for (int i = 0; i < 4; ++i)
#pragma unroll
        for (int j = 0; j < 4; ++j) acc[i][j] = (f32x4){0.f, 0.f, 0.f, 0.f};

    const int nkt = K >> 6;
    for (int kt = 0; kt < nkt; ++kt) {
        const int k0 = kt << 6;
        if (AF32) {
            const float* A = (const float*)Av;
#pragma unroll
            for (int i = 0; i < 8; ++i) {
                int flat = i * 256 + t;               // 128 rows x 16 col-quads
                int row = flat >> 4, kc = (flat & 15) << 2;
                float4 v = *(const float4*)(A + (size_t)(m0 + row) * K + k0 + kc);
                uint2 r;
                r.x = (u32)f2bf_rne(v.x) | ((u32)f2bf_rne(v.y) << 16);
                r.y = (u32)f2bf_rne(v.z) | ((u32)f2bf_rne(v.w) << 16);
                *(uint2*)(As + row * 72 + kc) = r;
            }
        } else {
            const u16* A = (const u16*)Av;
#pragma unroll
            for (int i = 0; i < 4; ++i) {
                int flat = i * 256 + t;               // 128 rows x 8 col-octs
                int row = flat >> 3, kc = (flat & 7) << 3;
                *(uint4*)(As + row * 72 + kc) = *(const uint4*)(A + (size_t)(m0 + row) * K + k0 + kc);
            }
        }
        // B [K,N] fp32 -> Bs[n][k] bf16 (transpose in LDS; scalar writes)
#pragma unroll
        for (int i = 0; i < 8; ++i) {
            int flat = i * 256 + t;                   // 64 k-rows x 32 n-quads
            int kr = flat >> 5, nc = (flat & 31) << 2;
            float4 v = *(const float4*)(B + (size_t)(k0 + kr) * N + n0 + nc);
            Bs[(nc + 0) * 72 + kr] = f2bf_rne(v.x);
            Bs[(nc + 1) * 72 + kr] = f2bf_rne(v.y);
            Bs[(nc + 2) * 72 + kr] = f2bf_rne(v.z);
            Bs[(nc + 3) * 72 + kr] = f2bf_rne(v.w);
        }
        __syncthreads();
#pragma unroll
        for (int ks = 0; ks < 2; ++ks) {
            s16x8 af[4], bfr[4];
#pragma unroll
            for (int mt = 0; mt < 4; ++mt)
                af[mt] = *(const s16x8*)(As + (wm + mt * 16 + ml) * 72 + ks * 32 + kq * 8);
#pragma unroll
            for (int nt = 0; nt < 4; ++nt)
                bfr[nt] = *(const s16x8*)(Bs + (wn + nt * 16 + ml) * 72 + ks * 32 + kq * 8);
#pragma unroll
            for (int mt = 0; mt < 4; ++mt)
#pragma unroll
                for (int nt = 0; nt < 4; ++nt)
                    acc[mt][nt] = __builtin_amdgcn_mfma_f32_16x16x32_bf16(af[mt], bfr[nt], acc[mt][nt], 0, 0, 0);
        }
        __syncthreads();
    }
#pragma unroll
    for (int mt = 0; mt < 4; ++mt)
#pragma unroll
        for (int nt = 0; nt < 4; ++nt)
#pragma unroll
            for (int r = 0; r < 4; ++r) {
                int row = m0 + wm + mt * 16 + kq * 4 + r;
                int col = n0 + wn + nt * 16 + ml;
                float v = acc[mt][nt][r];
                if (F32OUT)
                    ((float*)Cv)[(size_t)row * N + col] = v;
                else
                    ((u16*)Cv)[(size_t)row * N + col] = f2bf_rne(v);
            }
}

// ------------- conv(K=4) + silu + l2norm + beta-fold prep -------------
__global__ __launch_bounds__(512) void prep_kernel(const u16* __restrict__ Cmix,
                                                   const float* __restrict__ conv_w,
                                                   const float* __restrict__ beta,
                                                   u16* __restrict__ qn,
                                                   u16* __restrict__ kn,
                                                   u16* __restrict__ vb) {
    const int s = blockIdx.x;
    const int t = threadIdx.x;
    const int c8 = t << 3;
    __shared__ float ssq[16];
    if (t < 16) ssq[t] = 0.f;

    float y[8];
#pragma unroll
    for (int i = 0; i < 8; ++i) y[i] = 0.f;
    {
        uint4 mrow[4];
#pragma unroll
        for (int j = 0; j < 4; ++j) {
            int r = s - 3 + j;
            if (r >= 0) mrow[j] = *(const uint4*)(Cmix + (size_t)r * NQKV + c8);
            else        mrow[j] = uint4{0u, 0u, 0u, 0u};
        }
        float cw[8][4];
#pragma unroll
        for (int i = 0; i < 8; ++i) {
            float4 cv = *(const float4*)(conv_w + (size_t)(c8 + i) * 4);
            cw[i][0] = cv.x; cw[i][1] = cv.y; cw[i][2] = cv.z; cw[i][3] = cv.w;
        }
#pragma unroll
        for (int j = 0; j < 4; ++j) {
            float mf[8];
            unpack8(mrow[j], mf);
#pragma unroll
            for (int i = 0; i < 8; ++i) y[i] = fmaf(mf[i], cw[i][j], y[i]);
        }
#pragma unroll
        for (int i = 0; i < 8; ++i) {
            float v = y[i];
            y[i] = v / (1.f + expf(-v));
        }
    }
    __syncthreads();
    if (t < 256) {
        float p = 0.f;
#pragma unroll
        for (int i = 0; i < 8; ++i) p += y[i] * y[i];
        atomicAdd(&ssq[t >> 4], p);
    }
    __syncthreads();
    if (t < 128) {  // q, heads 0..7
        float rn = rsqrtf(ssq[t >> 4] + EPSF) * 0.08838834764831845f;  // * DK^-0.5
        float ov[8];
#pragma unroll
        for (int i = 0; i < 8; ++i) ov[i] = y[i] * rn;
        *(uint4*)(qn + (size_t)s * 1024 + c8) = pack8(ov);
    } else if (t < 256) {  // k, heads 0..7
        float rn = rsqrtf(ssq[t >> 4] + EPSF);
        float ov[8];
#pragma unroll
        for (int i = 0; i < 8; ++i) ov[i] = y[i] * rn;
        *(uint4*)(kn + (size_t)s * 1024 + (c8 - 1024)) = pack8(ov);
    } else {  // v * beta
        int vh = (c8 - 2048) >> 7;
        float bb = beta[s * 16 + vh];
        float ov[8];
#pragma unroll
        for (int i = 0; i < 8; ++i) ov[i] = y[i] * bb;
        *(uint4*)(vb + (size_t)s * 2048 + (c8 - 2048)) = pack8(ov);
    }
}

// ------------- per-(chunk,head) precompute -------------
__global__ __launch_bounds__(256) void precomp_kernel(const u16* __restrict__ qn,
                                                      const u16* __restrict__ kn,
                                                      const u16* __restrict__ vb,
                                                      const float* __restrict__ g,
                                                      const float* __restrict__ beta,
                                                      u16* __restrict__ uT,
                                                      u16* __restrict__ wT,
                                                      u16* __restrict__ qT,
                                                      u16* __restrict__ aqkT,
                                                      float* __restrict__ egc_arr,
                                                      float* __restrict__ ekd_arr,
                                                      float* __restrict__ eg) {
    const int b = blockIdx.x;  // n*16 + h
    const int n = b >> 4, h = b & 15, hs = h >> 1;
    const int t = threadIdx.x;
    const int s0 = n * 64;

    __shared__ u16 sK[64 * 128];
    __shared__ u16 sVQ[64 * 128];      // v*beta tile, later reused as q tile
    __shared__ float Am[64 * 65];      // A, then T in-place
    __shared__ float gc[64], bet[64], bexp[64], egc[64], ekd[64];

#pragma unroll
    for (int i = 0; i < 4; ++i) {
        int flat = i * 256 + t;
        int c = flat >> 4, dc = (flat & 15) << 3;
        *(uint4*)(sK + c * 128 + dc)  = *(const uint4*)(kn + (size_t)(s0 + c) * 1024 + hs * 128 + dc);
        *(uint4*)(sVQ + c * 128 + dc) = *(const uint4*)(vb + (size_t)(s0 + c) * 2048 + h * 128 + dc);
    }
    if (t < 64) {
        gc[t] = g[(size_t)(s0 + t) * 16 + h];
        bet[t] = beta[(size_t)(s0 + t) * 16 + h];
    }
    __syncthreads();
    if (t == 0) {
        float run = 0.f;
        for (int c = 0; c < 64; ++c) { run += gc[c]; gc[c] = run; }
    }
    __syncthreads();
    if (t < 64) {
        float e = expf(gc[t]);
        float ek = expf(gc[63] - gc[t]);
        bexp[t] = bet[t] * e;
        egc[t] = e;
        ekd[t] = ek;
        egc_arr[b * 64 + t] = e;
        ekd_arr[b * 64 + t] = ek;
    }
    if (t == 0) eg[b] = expf(gc[63]);
    __syncthreads();

    // A[i][j] = -(k_beta_i . k_j) * exp(gc_i - gc_j), strictly lower
#pragma unroll 1
    for (int r = 0; r < 16; ++r) {
        int e = t + 256 * r;
        int i = e >> 6, j = e & 63;
        float val = 0.f;
        if (j < i) {
            float dot = 0.f;
            for (int d = 0; d < 128; d += 8) {
                float kf[8], kg[8];
                unpack8(*(const uint4*)(sK + i * 128 + d), kf);
                unpack8(*(const uint4*)(sK + j * 128 + d), kg);
#pragma unroll
                for (int q = 0; q < 8; ++q) dot = fmaf(kf[q], kg[q], dot);
            }
            val = -dot * bet[i] * expf(gc[i] - gc[j]);
        }
        Am[i * 65 + j] = val;
    }
    __syncthreads();

    // T = (I - A)^{-1} by forward substitution, in place
    if (t < 64) Am[t] = (t == 0) ? 1.f : 0.f;
    __syncthreads();
    for (int i = 1; i < 64; ++i) {
        float val = 0.f;
        if (t < 64) {
            for (int j = 0; j < i; ++j) val = fmaf(Am[i * 65 + j], Am[j * 65 + t], val);
            if (t == i) val += 1.f;
        }
        __syncthreads();
        if (t < 64) Am[i * 65 + t] = val;
        __syncthreads();
    }

    // u = T @ (k*beta*exp(gc)),  w = T @ v   (stored transposed [d][c])
    {
        const int c = t >> 2;
        const int dq = (t & 3) << 5;
        float accu[32], accw[32];
#pragma unroll
        for (int dd = 0; dd < 32; ++dd) { accu[dd] = 0.f; accw[dd] = 0.f; }
        for (int j = 0; j < 64; ++j) {
            float tc = Am[c * 65 + j];
            float tu = tc * bexp[j];
#pragma unroll
            for (int d8 = 0; d8 < 32; d8 += 8) {
                float kf[8], vf[8];
                unpack8(*(const uint4*)(sK + j * 128 + dq + d8), kf);
                unpack8(*(const uint4*)(sVQ + j * 128 + dq + d8), vf);
#pragma unroll
                for (int q = 0; q < 8; ++q) {
                    accu[d8 + q] = fmaf(tu, kf[q], accu[d8 + q]);
                    accw[d8 + q] = fmaf(tc, vf[q], accw[d8 + q]);
                }
            }
        }
        for (int dd = 0; dd < 32; ++dd) {
            int d = dq + dd;
            uT[(size_t)b * 8192 + d * 64 + c] = f2bf_rne(accu[dd]);
            wT[(size_t)b * 8192 + d * 64 + c] = f2bf_rne(accw[dd]);
        }
    }

    __syncthreads();  // done with sVQ as v-tile; reload as q-tile
#pragma unroll
    for (int i = 0; i < 4; ++i) {
        int flat = i * 256 + t;
        int c = flat >> 4, dc = (flat & 15) << 3;
        *(uint4*)(sVQ + c * 128 + dc) = *(const uint4*)(qn + (size_t)(s0 + c) * 1024 + hs * 128 + dc);
    }
    __syncthreads();

    // AqkT[j][i] = (q_i . k_j) * exp(gc_i - gc_j) for j<=i else 0
#pragma unroll 1
    for (int r = 0; r < 16; ++r) {
        int e = t + 256 * r;
        int j = e >> 6, i = e & 63;
        float val = 0.f;
        if (j <= i) {
            float dot = 0.f;
            for (int d = 0; d < 128; d += 8) {
                float qf[8], kf[8];
                unpack8(*(const uint4*)(sVQ + i * 128 + d), qf);
                unpack8(*(const uint4*)(sK + j * 128 + d), kf);
#pragma unroll
                for (int q = 0; q < 8; ++q) dot = fmaf(qf[q], kf[q], dot);
            }
            val = dot * expf(gc[i] - gc[j]);
        }
        aqkT[(size_t)b * 4096 + e] = f2bf_rne(val);
    }

    // qT[hs][dk][s] = normed q transposed (written once per key head: h even)
    if ((h & 1) == 0) {
#pragma unroll 1
        for (int r = 0; r < 32; ++r) {
            int e = t + 256 * r;
            int dk = e >> 6, c = e & 63;
            qT[(size_t)(hs * 128 + dk) * S_LEN + s0 + c] = sVQ[c * 128 + dk];
        }
    }
}

// ------------- sequential inter-chunk scan; wave per dv column -------------
__global__ __launch_bounds__(256) void scan_kernel(const u16* __restrict__ uT,
                                                   const u16* __restrict__ qT,
                                                   const u16* __restrict__ wT,
                                                   const u16* __restrict__ kn,
                                                   const u16* __restrict__ aqkT,
                                                   const float* __restrict__ egc_arr,
                                                   const float* __restrict__ ekd_arr,
                                                   const float* __restrict__ eg,
                                                   u16* __restrict__ o) {
    const int h = blockIdx.x >> 5;
    const int hs = h >> 1;
    const int dvg = (blockIdx.x & 31) << 2;
    const int w = threadIdx.x >> 6;
    const int dv = dvg + w;
    const int c = threadIdx.x & 63;
    __shared__ float sc[4][128];
    __shared__ float vn[4][64];
    __shared__ float vnk[4][64];
    __shared__ float olds[256];
    sc[w][c] = 0.f;
    sc[w][c + 64] = 0.f;
    for (int n = 0; n < NCHUNK; ++n) {
        const int b = n * 16 + h;
        const int s0 = n * 64;
        const size_t b8 = (size_t)b * 8192;
        float v_acc = bfraw2f(wT[b8 + dv * 64 + c]);
        float oq = 0.f;
        const u16* qTb = qT + (size_t)hs * 128 * S_LEN + s0;
#pragma unroll 8
        for (int dk = 0; dk < 128; ++dk) {
            float s = sc[w][dk];
            v_acc = fmaf(-bfraw2f(uT[b8 + dk * 64 + c]), s, v_acc);
            oq    = fmaf( bfraw2f(qTb[(size_t)dk * S_LEN + c]), s, oq);
        }
        float o_acc = oq * egc_arr[b * 64 + c];
        vn[w][c] = v_acc;
        vnk[w][c] = v_acc * ekd_arr[b * 64 + c];
        __syncthreads();
        const size_t b4 = (size_t)b * 4096;
#pragma unroll 8
        for (int j = 0; j < 64; ++j)
            o_acc = fmaf(bfraw2f(aqkT[b4 + j * 64 + c]), vn[w][j], o_acc);
        const float egl = eg[b];
        float s0v = sc[w][c] * egl, s1v = sc[w][c + 64] * egl;
#pragma unroll 8
        for (int j = 0; j < 64; ++j) {
            const u16* kr = kn + (size_t)(s0 + j) * 1024 + hs * 128;
            float vv = vnk[w][j];
            s0v = fmaf(bfraw2f(kr[c]), vv, s0v);
            s1v = fmaf(bfraw2f(kr[c + 64]), vv, s1v);
        }
        sc[w][c] = s0v;
        sc[w][c + 64] = s1v;
        olds[c * 4 + w] = o_acc;
        __syncthreads();
        if (w == 0) {
            uint2 r;
            r.x = (u32)f2bf_rne(olds[c * 4 + 0]) | ((u32)f2bf_rne(olds[c * 4 + 1]) << 16);
            r.y = (u32)f2bf_rne(olds[c * 4 + 2]) | ((u32)f2bf_rne(olds[c * 4 + 3]) << 16);
            *(uint2*)(o + (size_t)(s0 + c) * 2048 + h * 128 + dvg) = r;
        }
        __syncthreads();
    }
}

// ------------- gated rmsnorm * silu(z) -> bf16 -------------
__global__ __launch_bounds__(256) void gate_kernel(const u16* __restrict__ o,
                                                   const u16* __restrict__ Cz,
                                                   const float* __restrict__ norm_w,
                                                   u16* __restrict__ gated) {
    const int s = blockIdx.x, t = threadIdx.x;
    const int c8 = t << 3, hh = t >> 4;
    __shared__ float ssq[16];
    if (t < 16) ssq[t] = 0.f;
    float ov[8];
    unpack8(*(const uint4*)(o + (size_t)s * 2048 + c8), ov);
    float p = 0.f;
#pragma unroll
    for (int i = 0; i < 8; ++i) p += ov[i] * ov[i];
    __syncthreads();
    atomicAdd(&ssq[hh], p);
    __syncthreads();
    const float rms = rsqrtf(ssq[hh] * 0.0078125f + EPSF);
    float zf[8];
    unpack8(*(const uint4*)(Cz + (size_t)s * 2048 + c8), zf);
    const int d0 = c8 & 127;
    float res[8];
#pragma unroll
    for (int i = 0; i < 8; ++i) {
        float z = zf[i];
        float sz = z / (1.f + expf(-z));
        res[i] = ov[i] * rms * norm_w[d0 + i] * sz;
    }
    *(uint4*)(gated + (size_t)s * 2048 + c8) = pack8(res);
}

extern "C" void kernel_launch(void* const* d_in, const int* in_sizes, int n_in,
                              void* d_out, int out_size, void* d_ws, size_t ws_size,
                              hipStream_t stream) {
    (void)in_sizes; (void)n_in; (void)out_size; (void)ws_size;
    const float* x       = (const float*)d_in[0];
    const float* W_qkv   = (const float*)d_in[1];
    const float* W_z     = (const float*)d_in[2];
    const float* W_b     = (const float*)d_in[3];
    const float* W_a     = (const float*)d_in[4];
    const float* conv_w  = (const float*)d_in[5];
    const float* A_log   = (const float*)d_in[6];
    const float* dt_bias = (const float*)d_in[7];
    const float* norm_w  = (const float*)d_in[8];
    const float* W_out   = (const float*)d_in[9];

    // ---- static workspace layout: 186,654,720 B = 178.0 MiB total ----
    char* p = (char*)d_ws;
    auto alloc = [&](size_t bytes) {
        char* r = p;
        p += (bytes + 255) & ~(size_t)255;
        return r;
    };
    u16* Cmix     = (u16*)alloc((size_t)S_LEN * NQKV * 2);            // 67.1 MB
    u16* qn       = (u16*)alloc((size_t)S_LEN * HKN * DKD * 2);       // 16.8 MB
    u16* kn       = (u16*)alloc((size_t)S_LEN * HKN * DKD * 2);       // 16.8 MB (live thru scan)
    u16* vb       = (u16*)alloc((size_t)S_LEN * HVN * DVD * 2);       // 33.5 MB
    u16* uT       = (u16*)alloc((size_t)NCHUNK * HVN * DKD * CLEN * 2); // 33.5 MB
    u16* qT       = (u16*)alloc((size_t)HKN * DKD * S_LEN * 2);       // 16.8 MB
    float* egc    = (float*)alloc((size_t)NCHUNK * HVN * CLEN * 4);   //  0.5 MB
    float* ekd    = (float*)alloc((size_t)NCHUNK * HVN * CLEN * 4);   //  0.5 MB
    float* eg     = (float*)alloc((size_t)NCHUNK * HVN * 4);          //  8 KB
    float* beta   = (float*)alloc((size_t)S_LEN * HVN * 4);           //  0.5 MB
    float* g      = (float*)alloc((size_t)S_LEN * HVN * 4);           //  0.5 MB
    // lifetime-disjoint overlays:
    u16* wT    = Cmix;                                   // [0, 33.5M) after prep consumed Cmix
    u16* aqkT  = Cmix + (size_t)16777216;                // [33.5M, 50.3M)
    u16* o_buf = Cmix + (size_t)25165824;                // [50.3M, 83.9M) = Cmix tail + qn
    u16* Cz    = vb;                                     // z-GEMM after precomp read vb
    u16* gated = uT;                                     // gate after scan read uT

    // 1) beta, g
    ba_kernel<<<S_LEN / 8, 256, 0, stream>>>(x, W_b, W_a, A_log, dt_bias, beta, g);
    // 2) mixed qkv GEMM (A fp32, B fp32 [K,N], bf16 out)
    gemm_kn<1, 0><<<dim3(NQKV / 128, S_LEN / 128), 256, 0, stream>>>(x, W_qkv, Cmix, S_LEN, NQKV, HID);
    // 3) conv + silu + l2norm prep
    prep_kernel<<<S_LEN, 512, 0, stream>>>(Cmix, conv_w, beta, qn, kn, vb);
    // 4) per-chunk precompute (writes wT/aqkT over dead Cmix)
    precomp_kernel<<<NCHUNK * HVN, 256, 0, stream>>>(qn, kn, vb, g, beta, uT, wT, qT, aqkT, egc, ekd, eg);
    // 5) z GEMM (over dead vb)
    gemm_kn<1, 0><<<dim3(HID / 128, S_LEN / 128), 256, 0, stream>>>(x, W_z, Cz, S_LEN, HID, HID);
    // 6) sequential scan
    scan_kernel<<<HVN * 32, 256, 0, stream>>>(uT, qT, wT, kn, aqkT, egc, ekd, eg, o_buf);
    // 7) gated rmsnorm (gated over dead uT)
    gate_kernel<<<S_LEN, 256, 0, stream>>>(o_buf, Cz, norm_w, gated);
    // 8) output projection -> fp32 d_out
    gemm_kn<0, 1><<<dim3(HID / 128, S_LEN / 128), 256, 0, stream>>>(gated, W_out, d_out, S_LEN, HID, HID);
}